// Round 17
// baseline (1190.762 us; speedup 1.0000x reference)
//
#include <hip/hip_runtime.h>

#define BB 256
#define SEQ 512
#define IDIM 32
#define HDIM 128
#define ODIM 64
// ETDRK4 (Cox-Matthews), dt=1/2: linear part exact, 8 stages/timestep.
// Verified R15/R16: absmax 0.015625 vs threshold 0.0497. dt=1 ruled out
// (error ~16x, est >0.1). Stage count is at the algorithmic floor.
#define NSUB_SIM 2

typedef float v2f __attribute__((ext_vector_type(2)));
typedef _Float16 hf;
typedef hf h2 __attribute__((ext_vector_type(2)));
typedef hf h8 __attribute__((ext_vector_type(8)));

template <int CTRL>
__device__ __forceinline__ float dpp_add(float x) {
    int yi = __builtin_amdgcn_mov_dpp(__float_as_int(x), CTRL, 0xF, 0xF, false);
    return x + __int_as_float(yi);
}

__device__ __forceinline__ float fdot2(h2 a, h2 b, float c) {
#if __has_builtin(__builtin_amdgcn_fdot2)
    return __builtin_amdgcn_fdot2(a, b, c, false);
#else
    float r = c;
    asm volatile("v_dot2_f32_f16 %0, %1, %2, %0" : "+v"(r) : "v"(a), "v"(b));
    return r;
#endif
}

// One block (= one chain) per CU, 256 threads = 4 waves.
// R17 tiling: lane (row = tid>>1, c = tid&1) owns ONE row x k-half
// [64c, 64c+64). Per stage: 1 ds_write_b16 (pair-dup, collapses) +
// lgkm-only s_barrier + 8 ds_read_b128 (2-addr/bank broadcast, free) +
// 32 v_dot2_f32_f16 (4 chains, 8-deep) + ONE dpp_add (xor1) + local tail.
// vs R16: butterfly 2->1 level, no rsel select; dot issue unchanged.
__global__ __launch_bounds__(256, 1) void lnn_recur(
    const float* __restrict__ x,
    const float* __restrict__ Wx,
    const float* __restrict__ Wh,
    const float* __restrict__ bias,
    const float* __restrict__ tau,
    float* __restrict__ hs)
{
    __shared__ __align__(16) hf abh[2][HDIM];
    const int b    = blockIdx.x;
    const int tid  = threadIdx.x;
    const int row  = tid >> 1;      // one row per lane pair
    const int c    = tid & 1;       // k-half [64c, 64c+64)
    const bool pub = (c == 0);      // publisher lane for the global h store

    const float K2E = 2.885390081777927f;  // 2*log2(e); tanh(z)=1-2/(1+exp2(K2E*z))

    // Wh row x k-half as f16 pairs scaled by K2E (32 VGPR)
    h2 w[32];
    {
        const float* p = Wh + row * HDIM + 64 * c;
        #pragma unroll
        for (int m = 0; m < 32; ++m)
            w[m] = h2{(hf)(p[2*m] * K2E), (hf)(p[2*m+1] * K2E)};
    }
    // Wx row x x-half [16c, 16c+16), scaled by K2E (8 v2f = 16 VGPR)
    v2f wx[8];
    {
        const float* p = Wx + row * IDIM + 16 * c;
        #pragma unroll
        for (int m = 0; m < 8; ++m)
            wx[m] = v2f{p[2*m] * K2E, p[2*m+1] * K2E};
    }
    const float biasK = K2E * bias[row];

    // ETDRK4 per-row coefficients (verified R15/R16)
    const float DT  = 1.0f / (float)NSUB_SIM;
    const float tp  = fabsf(tau[row]) + 0.001f;
    const float zz  = -DT / tp;
    const float Ee  = expf(zz);
    const float E2  = expf(0.5f * zz);
    const float Qa  = 1.0f - E2;
    const float iz2 = 1.0f / (zz * zz);
    const float f1a  = -(-4.0f - zz + Ee * (4.0f - 3.0f * zz + zz * zz)) * iz2;
    const float f2a2 = -2.0f * (2.0f + zz + Ee * (zz - 2.0f)) * iz2;
    const float f3a  = -(-4.0f - 3.0f * zz - zz * zz + Ee * (4.0f - zz)) * iz2;

    float h  = 0.0f;
    int  par = 0;
    float cb = 0.0f;

    // x half [16c, 16c+16) = 4 float4, prefetched one timestep ahead
    float4 xv0 = *reinterpret_cast<const float4*>(x + ((size_t)b * SEQ) * IDIM + 16 * c + 0);
    float4 xv1 = *reinterpret_cast<const float4*>(x + ((size_t)b * SEQ) * IDIM + 16 * c + 4);
    float4 xv2 = *reinterpret_cast<const float4*>(x + ((size_t)b * SEQ) * IDIM + 16 * c + 8);
    float4 xv3 = *reinterpret_cast<const float4*>(x + ((size_t)b * SEQ) * IDIM + 16 * c + 12);

    #pragma unroll 1
    for (int t = 0; t < SEQ; ++t) {
        const int tn = (t + 1 < SEQ) ? (t + 1) : t;
        const float* xnp = x + ((size_t)b * SEQ + tn) * IDIM + 16 * c;
        float4 xn0 = *reinterpret_cast<const float4*>(xnp + 0);
        float4 xn1 = *reinterpret_cast<const float4*>(xnp + 4);
        float4 xn2 = *reinterpret_cast<const float4*>(xnp + 8);
        float4 xn3 = *reinterpret_cast<const float4*>(xnp + 12);

        // cbK = K2E*(x_t . Wx_row + bias): 1-level butterfly over k-half
        {
            v2f q0 = wx[0] * v2f{xv0.x, xv0.y} + wx[1] * v2f{xv0.z, xv0.w};
            v2f q1 = wx[2] * v2f{xv1.x, xv1.y} + wx[3] * v2f{xv1.z, xv1.w};
            v2f q2 = wx[4] * v2f{xv2.x, xv2.y} + wx[5] * v2f{xv2.z, xv2.w};
            v2f q3 = wx[6] * v2f{xv3.x, xv3.y} + wx[7] * v2f{xv3.z, xv3.w};
            v2f q  = (q0 + q1) + (q2 + q3);
            float d = q.x + q.y;
            d = dpp_add<0xB1>(d);   // + partner (lane^1) = full 32-k x-dot
            cb = d + biasK;
        }

        #pragma unroll 1
        for (int s = 0; s < NSUB_SIM; ++s) {
            // returns T = tanh(cb + Wh.a) for this lane's row; publishes a (f16)
            auto stage = [&](float a) -> float {
                abh[par][row] = (hf)a;   // pair-dup same-addr same-data write
                asm volatile("s_waitcnt lgkmcnt(0)" ::: "memory");
                __builtin_amdgcn_s_barrier();
                asm volatile("" ::: "memory");
                const h8* ap = reinterpret_cast<const h8*>(&abh[par][64 * c]);
                float p0 = 0.f, p1 = 0.f, p2 = 0.f, p3 = 0.f;
                #pragma unroll
                for (int i = 0; i < 8; ++i) {
                    h8 v = ap[i];
                    p0 = fdot2(w[4*i+0], h2{v[0], v[1]}, p0);
                    p1 = fdot2(w[4*i+1], h2{v[2], v[3]}, p1);
                    p2 = fdot2(w[4*i+2], h2{v[4], v[5]}, p2);
                    p3 = fdot2(w[4*i+3], h2{v[6], v[7]}, p3);
                }
                float d = (p0 + p1) + (p2 + p3);
                d = dpp_add<0xB1>(d);   // + partner k-half: full 128-dot
                par ^= 1;
                float e = __builtin_amdgcn_exp2f(cb + d);
                return 1.0f - 2.0f * __builtin_amdgcn_rcpf(1.0f + e);
            };

            // ETDRK4 (Cox-Matthews), diagonal L, N folded into coefficients
            float T1 = stage(h);
            float u  = E2 * h + Qa * T1;
            float T2 = stage(u);
            float bb = E2 * h + Qa * T2;
            float T3 = stage(bb);
            float cc = E2 * u + Qa * (2.0f * T3 - T1);
            float T4 = stage(cc);
            h = Ee * h + f1a * T1 + f2a2 * (T2 + T3) + f3a * T4;
        }

        xv0 = xn0; xv1 = xn1; xv2 = xn2; xv3 = xn3;
        if (pub) hs[((size_t)b * SEQ + t) * HDIM + row] = h;
    }
}

// outs[bt][o] = hs[bt] . Wout_row_o + bout[o]
__global__ __launch_bounds__(256) void lnn_out(
    const float* __restrict__ hs,
    const float* __restrict__ Wout,
    const float* __restrict__ bout,
    float* __restrict__ outs)
{
    __shared__ float wt[HDIM][ODIM + 1];
    const int tid = threadIdx.x;
    for (int i = tid; i < HDIM * ODIM; i += 256) {
        int o = i >> 7;
        int k = i & 127;
        wt[k][o] = Wout[i];
    }
    __syncthreads();

    const int o = tid & 63;
    const int r = tid >> 6;
    const float bo = bout[o];
    const int nbt = BB * SEQ;

    for (int bt = blockIdx.x * 4 + r; bt < nbt; bt += gridDim.x * 4) {
        const float4* hp = reinterpret_cast<const float4*>(hs + (size_t)bt * HDIM);
        float acc0 = bo, acc1 = 0.f, acc2 = 0.f, acc3 = 0.f;
        #pragma unroll
        for (int kk = 0; kk < 32; ++kk) {
            float4 v = hp[kk];
            acc0 += v.x * wt[4*kk+0][o];
            acc1 += v.y * wt[4*kk+1][o];
            acc2 += v.z * wt[4*kk+2][o];
            acc3 += v.w * wt[4*kk+3][o];
        }
        outs[(size_t)bt * ODIM + o] = (acc0 + acc1) + (acc2 + acc3);
    }
}

extern "C" void kernel_launch(void* const* d_in, const int* in_sizes, int n_in,
                              void* d_out, int out_size, void* d_ws, size_t ws_size,
                              hipStream_t stream) {
    const float* x    = (const float*)d_in[0];
    const float* Wx   = (const float*)d_in[1];
    const float* Wh   = (const float*)d_in[2];
    const float* bias = (const float*)d_in[3];
    const float* tau  = (const float*)d_in[4];
    const float* Wout = (const float*)d_in[5];
    const float* bout = (const float*)d_in[6];

    float* outs = (float*)d_out;
    float* hs   = outs + (size_t)BB * SEQ * ODIM;

    lnn_recur<<<BB, 256, 0, stream>>>(x, Wx, Wh, bias, tau, hs);
    lnn_out<<<2048, 256, 0, stream>>>(hs, Wout, bout, outs);
}

// Round 18
// 1133.507 us; speedup vs baseline: 1.0505x; 1.0505x over previous
//
#include <hip/hip_runtime.h>

#define BB 256
#define SEQ 512
#define IDIM 32
#define HDIM 128
#define ODIM 64
// ETDRK4 (Cox-Matthews), dt=1/2: linear part exact, 8 stages/timestep.
// Verified R15/R16: absmax 0.015625 vs threshold 0.0497. dt=1 ruled out
// (error ~16x, est >0.1). Stage count at algorithmic floor; R16 tiling is
// the measured optimum of the ablation matrix (R11-R17).
#define NSUB_SIM 2

typedef float v2f __attribute__((ext_vector_type(2)));
typedef _Float16 hf;
typedef hf h2 __attribute__((ext_vector_type(2)));
typedef hf h8 __attribute__((ext_vector_type(8)));

template <int CTRL>
__device__ __forceinline__ float dpp_add(float x) {
    int yi = __builtin_amdgcn_mov_dpp(__float_as_int(x), CTRL, 0xF, 0xF, false);
    return x + __int_as_float(yi);
}

__device__ __forceinline__ float fdot2(h2 a, h2 b, float c) {
#if __has_builtin(__builtin_amdgcn_fdot2)
    return __builtin_amdgcn_fdot2(a, b, c, false);
#else
    float r = c;
    asm volatile("v_dot2_f32_f16 %0, %1, %2, %0" : "+v"(r) : "v"(a), "v"(b));
    return r;
#endif
}

// One block (= one chain) per CU, 256 threads = 4 waves (R16 structure).
// Lane (g = tid>>2, c = tid&3) owns rows {2g, 2g+1} x k-chunk [32c, 32c+32).
// f16 weights (32 VGPR). Per stage: 1 ds_write_b16 (dup-collapsed) +
// lgkm-only s_barrier + 4 ds_read_b128 (2-way/bank broadcast, free) +
// 32 v_dot2_f32_f16 (4 chains, 8-deep) + 2-level DPP butterfly (0xB1, 0x4E)
// + 1 cndmask + tanh tail. Measured 620 cyc/stage; serial-latency floor.
__global__ __launch_bounds__(256, 1) void lnn_recur(
    const float* __restrict__ x,
    const float* __restrict__ Wx,
    const float* __restrict__ Wh,
    const float* __restrict__ bias,
    const float* __restrict__ tau,
    float* __restrict__ hs)
{
    __shared__ __align__(16) hf abh[2][HDIM];
    const int b    = blockIdx.x;
    const int tid  = threadIdx.x;
    const int g    = tid >> 2;      // row pair: rows 2g, 2g+1  (g in [0,64))
    const int c    = tid & 3;       // k-chunk [32c, 32c+32)
    const int rsel = c & 1;         // this lane's tail row: 2g+rsel
    const int row  = 2 * g + rsel;
    const bool pub = (c < 2);       // publisher lanes for the global h store

    const float K2E = 2.885390081777927f;  // 2*log2(e); tanh(z)=1-2/(1+exp2(K2E*z))

    // Wh rows 2g,2g+1 x k-chunk as f16 pairs scaled by K2E (32 VGPR)
    h2 w0[16], w1[16];
    {
        const float* p0 = Wh + (2 * g + 0) * HDIM + 32 * c;
        const float* p1 = Wh + (2 * g + 1) * HDIM + 32 * c;
        #pragma unroll
        for (int m = 0; m < 16; ++m) {
            w0[m] = h2{(hf)(p0[2*m] * K2E), (hf)(p0[2*m+1] * K2E)};
            w1[m] = h2{(hf)(p1[2*m] * K2E), (hf)(p1[2*m+1] * K2E)};
        }
    }
    // Wx rows 2g,2g+1 x x-chunk [8c, 8c+8), scaled by K2E (f32 v2f, 16 VGPR)
    v2f wx[2][4];
    #pragma unroll
    for (int r = 0; r < 2; ++r) {
        const float* p = Wx + (2 * g + r) * IDIM + 8 * c;
        #pragma unroll
        for (int m = 0; m < 4; ++m)
            wx[r][m] = v2f{p[2*m] * K2E, p[2*m+1] * K2E};
    }
    const float biasK = K2E * bias[row];

    // ETDRK4 per-row coefficients (verified R15/R16)
    const float DT  = 1.0f / (float)NSUB_SIM;
    const float tp  = fabsf(tau[row]) + 0.001f;
    const float zz  = -DT / tp;
    const float Ee  = expf(zz);
    const float E2  = expf(0.5f * zz);
    const float Qa  = 1.0f - E2;
    const float iz2 = 1.0f / (zz * zz);
    const float f1a  = -(-4.0f - zz + Ee * (4.0f - 3.0f * zz + zz * zz)) * iz2;
    const float f2a2 = -2.0f * (2.0f + zz + Ee * (zz - 2.0f)) * iz2;
    const float f3a  = -(-4.0f - 3.0f * zz - zz * zz + Ee * (4.0f - zz)) * iz2;

    float h  = 0.0f;
    int  par = 0;
    float cb = 0.0f;

    // x chunk [8c, 8c+8) = 2 float4, prefetched one timestep ahead
    float4 xv0 = *reinterpret_cast<const float4*>(x + ((size_t)b * SEQ) * IDIM + 8 * c);
    float4 xv1 = *reinterpret_cast<const float4*>(x + ((size_t)b * SEQ) * IDIM + 8 * c + 4);

    #pragma unroll 1
    for (int t = 0; t < SEQ; ++t) {
        const int tn = (t + 1 < SEQ) ? (t + 1) : t;
        float4 xn0 = *reinterpret_cast<const float4*>(x + ((size_t)b * SEQ + tn) * IDIM + 8 * c);
        float4 xn1 = *reinterpret_cast<const float4*>(x + ((size_t)b * SEQ + tn) * IDIM + 8 * c + 4);

        // cbK = K2E*(x_t . Wx_row + bias): 2-level butterfly over c, sel2
        {
            v2f xa0 = v2f{xv0.x, xv0.y}, xa1 = v2f{xv0.z, xv0.w};
            v2f xa2 = v2f{xv1.x, xv1.y}, xa3 = v2f{xv1.z, xv1.w};
            float p[2];
            #pragma unroll
            for (int r = 0; r < 2; ++r) {
                v2f q = (wx[r][0] * xa0 + wx[r][1] * xa1)
                      + (wx[r][2] * xa2 + wx[r][3] * xa3);
                float d = q.x + q.y;
                d = dpp_add<0xB1>(d);   // + (c^1)
                d = dpp_add<0x4E>(d);   // + (c^2): full 32-k sum
                p[r] = d;
            }
            cb = (rsel ? p[1] : p[0]) + biasK;
        }

        #pragma unroll 1
        for (int s = 0; s < NSUB_SIM; ++s) {
            // returns T = tanh(cb + Wh.a) for this lane's row; publishes a (f16)
            auto stage = [&](float a) -> float {
                abh[par][row] = (hf)a;   // 2-dup same-addr same-data write
                asm volatile("s_waitcnt lgkmcnt(0)" ::: "memory");
                __builtin_amdgcn_s_barrier();
                asm volatile("" ::: "memory");
                const h8* ap = reinterpret_cast<const h8*>(&abh[par][32 * c]);
                h8 q0 = ap[0], q1 = ap[1], q2 = ap[2], q3 = ap[3];
                float p0a = 0.f, p0b = 0.f, p1a = 0.f, p1b = 0.f;
                #pragma unroll
                for (int j = 0; j < 4; ++j) {
                    h2 A0 = h2{q0[2*j], q0[2*j+1]};
                    h2 A1 = h2{q1[2*j], q1[2*j+1]};
                    h2 A2 = h2{q2[2*j], q2[2*j+1]};
                    h2 A3 = h2{q3[2*j], q3[2*j+1]};
                    p0a = fdot2(w0[j],      A0, p0a);
                    p0b = fdot2(w0[4 + j],  A1, p0b);
                    p0a = fdot2(w0[8 + j],  A2, p0a);
                    p0b = fdot2(w0[12 + j], A3, p0b);
                    p1a = fdot2(w1[j],      A0, p1a);
                    p1b = fdot2(w1[4 + j],  A1, p1b);
                    p1a = fdot2(w1[8 + j],  A2, p1a);
                    p1b = fdot2(w1[12 + j], A3, p1b);
                }
                float d0 = p0a + p0b;
                float d1 = p1a + p1b;
                d0 = dpp_add<0xB1>(d0); d0 = dpp_add<0x4E>(d0);
                d1 = dpp_add<0xB1>(d1); d1 = dpp_add<0x4E>(d1);
                par ^= 1;
                float dd = rsel ? d1 : d0;
                float e  = __builtin_amdgcn_exp2f(cb + dd);
                return 1.0f - 2.0f * __builtin_amdgcn_rcpf(1.0f + e);
            };

            // ETDRK4 (Cox-Matthews), diagonal L, N folded into coefficients
            float T1 = stage(h);
            float u  = E2 * h + Qa * T1;
            float T2 = stage(u);
            float bb = E2 * h + Qa * T2;
            float T3 = stage(bb);
            float cc = E2 * u + Qa * (2.0f * T3 - T1);
            float T4 = stage(cc);
            h = Ee * h + f1a * T1 + f2a2 * (T2 + T3) + f3a * T4;
        }

        xv0 = xn0; xv1 = xn1;
        if (pub) hs[((size_t)b * SEQ + t) * HDIM + row] = h;
    }
}

// outs[bt][o] = hs[bt] . Wout_row_o + bout[o]
__global__ __launch_bounds__(256) void lnn_out(
    const float* __restrict__ hs,
    const float* __restrict__ Wout,
    const float* __restrict__ bout,
    float* __restrict__ outs)
{
    __shared__ float wt[HDIM][ODIM + 1];
    const int tid = threadIdx.x;
    for (int i = tid; i < HDIM * ODIM; i += 256) {
        int o = i >> 7;
        int k = i & 127;
        wt[k][o] = Wout[i];
    }
    __syncthreads();

    const int o = tid & 63;
    const int r = tid >> 6;
    const float bo = bout[o];
    const int nbt = BB * SEQ;

    for (int bt = blockIdx.x * 4 + r; bt < nbt; bt += gridDim.x * 4) {
        const float4* hp = reinterpret_cast<const float4*>(hs + (size_t)bt * HDIM);
        float acc0 = bo, acc1 = 0.f, acc2 = 0.f, acc3 = 0.f;
        #pragma unroll
        for (int kk = 0; kk < 32; ++kk) {
            float4 v = hp[kk];
            acc0 += v.x * wt[4*kk+0][o];
            acc1 += v.y * wt[4*kk+1][o];
            acc2 += v.z * wt[4*kk+2][o];
            acc3 += v.w * wt[4*kk+3][o];
        }
        outs[(size_t)bt * ODIM + o] = (acc0 + acc1) + (acc2 + acc3);
    }
}

extern "C" void kernel_launch(void* const* d_in, const int* in_sizes, int n_in,
                              void* d_out, int out_size, void* d_ws, size_t ws_size,
                              hipStream_t stream) {
    const float* x    = (const float*)d_in[0];
    const float* Wx   = (const float*)d_in[1];
    const float* Wh   = (const float*)d_in[2];
    const float* bias = (const float*)d_in[3];
    const float* tau  = (const float*)d_in[4];
    const float* Wout = (const float*)d_in[5];
    const float* bout = (const float*)d_in[6];

    float* outs = (float*)d_out;
    float* hs   = outs + (size_t)BB * SEQ * ODIM;

    lnn_recur<<<BB, 256, 0, stream>>>(x, Wx, Wh, bias, tau, hs);
    lnn_out<<<2048, 256, 0, stream>>>(hs, Wout, bout, outs);
}